// Round 1
// baseline (125.046 us; speedup 1.0000x reference)
//
#include <hip/hip_runtime.h>
#include <math.h>

#define BS   16
#define NQ   128
#define NCLS 3
#define T    480
#define P    72
#define BN   (BS * NQ)      // 2048
#define TROW (5 + 2 * P)    // 149
#define KBN  8              // bn per block
#define NTHR 1024

// Single fused kernel, NO workspace use (the 256 MiB ws re-poison fill was
// ~40 us of the 66.7 us graph). Each block (1/CU) computes ALL 480 targets'
// fp64 moments into LDS (phase 1), block-reduces per_min, then computes the
// cost matrix for its 8 bn's (phase 2). LDS total = 63,424 B (<64 KB).
__global__ __launch_bounds__(NTHR) void fused_kernel(
    const float* __restrict__ logits,
    const float* __restrict__ curves,
    const float* __restrict__ targets,
    float* __restrict__ out)
{
    // rows 0..6 : m_j = sum_valid lam^j
    // rows 7..10 : -2*sum_valid tx*lam^k ; rows 11..14: -2*sum_valid ty*lam^k
    // row 15 : Q = sum_valid tx^2+ty^2
    __shared__ double sMD[16 * T];   // 61440 B
    __shared__ float  sPER[T];       // 1920 B  (valid count per target)
    __shared__ float  swm[16];       // per-wave mins

    const int tid = threadIdx.x;

    // ---------------- phase 1: moments, 2 threads per target ----------------
    if (tid < 2 * T) {
        const int t    = tid >> 1;
        const int half = tid & 1;
        const float* row = targets + (size_t)t * TROW;
        const float ly = row[1], uy = row[2], lx = row[3], ux = row[4];
        const float dx = ux - lx, dy = uy - ly;
        const float nrm = sqrtf(dx * dx + dy * dy);

        double v[17];
#pragma unroll
        for (int i = 0; i < 17; ++i) v[i] = 0.0;

        const int p0 = half * (P / 2);
        for (int p = p0; p < p0 + P / 2; ++p) {
            float tx = row[5 + p];
            float ty = row[5 + P + p];
            if (tx >= 0.0f) {
                float lamf = dx * (tx - lx) + dy * (ty - ly);
                lamf = lamf / nrm / nrm;          // match reference: dot/nrm/nrm
                double L   = (double)lamf;
                double txd = (double)tx, tyd = (double)ty;
                double lp  = 1.0;
#pragma unroll
                for (int j = 0; j < 7; ++j) {
                    v[j] += lp;
                    if (j < 4) { v[7 + j] += txd * lp; v[11 + j] += tyd * lp; }
                    lp *= L;
                }
                v[15] += txd * txd + tyd * tyd;
                v[16] += 1.0;
            }
        }
        // combine the (half=0, half=1) pair — adjacent lanes, same wave
#pragma unroll
        for (int i = 0; i < 17; ++i) v[i] += __shfl_down(v[i], 1);

        if (half == 0) {
#pragma unroll
            for (int j = 0; j < 7; ++j) sMD[j * T + t] = v[j];
#pragma unroll
            for (int k = 0; k < 4; ++k) {
                sMD[(7 + k)  * T + t] = -2.0 * v[7 + k];
                sMD[(11 + k) * T + t] = -2.0 * v[11 + k];
            }
            sMD[15 * T + t] = v[15];
            sPER[t] = (float)v[16];
        }
    }
    __syncthreads();

    // ---------------- per_min over all 480 targets (block-local) ------------
    float pm = (tid < T) ? sPER[tid] : 1e30f;
#pragma unroll
    for (int off = 32; off > 0; off >>= 1) pm = fminf(pm, __shfl_xor(pm, off));
    if ((tid & 63) == 0) swm[tid >> 6] = pm;
    __syncthreads();
    float per_min = swm[0];
#pragma unroll
    for (int i = 1; i < 16; ++i) per_min = fminf(per_min, swm[i]);

    // ---------------- phase 2: cost matrix ----------------------------------
    const int g = tid >> 9;          // bn half-group: 0 or 1
    const int t = tid & 511;
    if (t >= T) return;

    double m[16];
#pragma unroll
    for (int r = 0; r < 16; ++r) m[r] = sMD[r * T + t];   // ds_read_b64, cheap

    const float* row = targets + (size_t)t * TROW;        // L2-hot header reload
    const float ly = row[1], uy = row[2], lx = row[3], ux = row[4];
    const int   id = (int)row[0];
    const float per = sPER[t];
    const float w = sqrtf(per_min / per);

    const int bnbase = blockIdx.x * KBN + g * (KBN / 2);
#pragma unroll
    for (int j = 0; j < KBN / 2; ++j) {
        const int bn = bnbase + j;
        const float* ob = curves + (size_t)bn * 8;        // wave-uniform -> broadcast
        float o0 = ob[0], o1 = ob[1], o2 = ob[2], o3 = ob[3];
        float o4 = ob[4], o5 = ob[5], o6 = ob[6], o7 = ob[7];
        float a0 = o2, a1 = o3 - o4 - o5 - o2, a2 = o5, a3 = o4;
        float b0 = o0, b1 = o1 - o6 - o7 - o0, b2 = o7, b3 = o6;

        double A0 = a0, A1 = a1, A2 = a2, A3 = a3;
        double B0 = b0, B1 = b1, B2 = b2, B3 = b3;
        double acc = m[15]
            + (A0 * A0 + B0 * B0) * m[0]
            + 2.0 * (A0 * A1 + B0 * B1) * m[1]
            + (2.0 * (A0 * A2 + B0 * B2) + A1 * A1 + B1 * B1) * m[2]
            + 2.0 * (A0 * A3 + A1 * A2 + B0 * B3 + B1 * B2) * m[3]
            + (2.0 * (A1 * A3 + B1 * B3) + A2 * A2 + B2 * B2) * m[4]
            + 2.0 * (A2 * A3 + B2 * B3) * m[5]
            + (A3 * A3 + B3 * B3) * m[6]
            + A0 * m[7]  + A1 * m[8]  + A2 * m[9]  + A3 * m[10]
            + B0 * m[11] + B1 * m[12] + B2 * m[13] + B3 * m[14];

        const float* lg = logits + (size_t)bn * NCLS;     // wave-uniform
        float l0 = lg[0], l1 = lg[1], l2 = lg[2];
        float mx = fmaxf(l0, fmaxf(l1, l2));
        float e0 = __expf(l0 - mx), e1 = __expf(l1 - mx), e2 = __expf(l2 - mx);
        float inv = 1.0f / (e0 + e1 + e2);
        float prob = (id == 0) ? e0 * inv : ((id == 1) ? e1 * inv : e2 * inv);

        float cp = (float)acc * w * 0.1f;
        float cl = 0.5f * (fabsf(b0 - ly) + fabsf(a0 - lx));
        float cu = 0.5f * (fabsf(o1 - uy) + fabsf(o3 - ux));
        out[(size_t)bn * T + t] = -prob + cp + cl + cu;   // coalesced over t
    }
}

extern "C" void kernel_launch(void* const* d_in, const int* in_sizes, int n_in,
                              void* d_out, int out_size, void* d_ws, size_t ws_size,
                              hipStream_t stream) {
    const float* logits  = (const float*)d_in[0];  // (16,128,3)
    const float* curves  = (const float*)d_in[1];  // (16,128,8)
    const float* targets = (const float*)d_in[2];  // (480,149)
    (void)d_ws; (void)ws_size;                     // workspace deliberately unused

    fused_kernel<<<BN / KBN, NTHR, 0, stream>>>(logits, curves, targets,
                                                (float*)d_out);
}

// Round 2
// 104.531 us; speedup vs baseline: 1.1963x; 1.1963x over previous
//
#include <hip/hip_runtime.h>
#include <hip/hip_cooperative_groups.h>
#include <math.h>

namespace cg = cooperative_groups;

#define BS   16
#define NQ   128
#define NCLS 3
#define T    480
#define P    72
#define BN   (BS * NQ)      // 2048
#define TROW (5 + 2 * P)    // 149
#define KBN  8              // bn per block in phase 2
#define NBLK (BN / KBN)     // 256 blocks
#define NTHR 1024
#define WPB  (NTHR / 64)    // 16 waves per block

// ws layout (the harness poisons ws unconditionally — round-1 proved the
// 256 MiB fill runs even when ws is unused, so scratch here is FREE):
//   MD  double[16][T] @ 0      (61440 B)
//     rows 0..6  : m_j  = sum_valid lam^j            (j=0..6)
//     rows 7..10 : sx_k = -2 * sum_valid tx*lam^k    (k=0..3)
//     rows 11..14: sy_k = -2 * sum_valid ty*lam^k    (k=0..3)
//     row  15    : Q    = sum_valid (tx^2 + ty^2)
//   EF  float[6][T]   @ 61440  (11520 B): ly, uy, lx, ux, per, id
#define MD_OFF_B 0
#define EF_OFF_B 61440

// Single cooperative kernel: phase 1 (coalesced per-wave moments, exactly the
// round-0 moments_kernel body) -> grid.sync() -> phase 2 (round-0 cost body).
// Removes one launch + inter-kernel gap; keeps all loads/stores coalesced.
__global__ __launch_bounds__(NTHR) void fused(
    const float* __restrict__ logits,
    const float* __restrict__ curves,
    const float* __restrict__ targets,
    double* __restrict__ MD,
    float* __restrict__ EF,
    float* __restrict__ out)
{
    const int tid  = threadIdx.x;
    const int lane = tid & 63;
    const int wid  = tid >> 6;

    // ---------- phase 1: one wave per target, spread across blocks ----------
    // t = blockIdx.x + 256*wid  -> every block has at most 2 busy waves.
    const int t1 = blockIdx.x + NBLK * wid;
    if (t1 < T) {
        const float* row = targets + (size_t)t1 * TROW;
        const float ly = row[1], uy = row[2], lx = row[3], ux = row[4];
        const float dx = ux - lx, dy = uy - ly;
        const float nrm = sqrtf(dx * dx + dy * dy);

        double v[17];
#pragma unroll
        for (int i = 0; i < 17; ++i) v[i] = 0.0;

        for (int p = lane; p < P; p += 64) {
            float tx = row[5 + p];          // coalesced across lanes
            float ty = row[5 + P + p];
            if (tx >= 0.0f) {
                float lamf = dx * (tx - lx) + dy * (ty - ly);
                lamf = lamf / nrm / nrm;    // match reference: dot/nrm/nrm
                double L   = (double)lamf;
                double txd = (double)tx, tyd = (double)ty;
                double lp  = 1.0;
#pragma unroll
                for (int j = 0; j < 7; ++j) {
                    v[j] += lp;
                    if (j < 4) { v[7 + j] += txd * lp; v[11 + j] += tyd * lp; }
                    lp *= L;
                }
                v[15] += txd * txd + tyd * tyd;
                v[16] += 1.0;
            }
        }
#pragma unroll
        for (int off = 32; off > 0; off >>= 1) {
#pragma unroll
            for (int i = 0; i < 17; ++i) v[i] += __shfl_down(v[i], off);
        }
        if (lane == 0) {
#pragma unroll
            for (int j = 0; j < 7; ++j) MD[j * T + t1] = v[j];
#pragma unroll
            for (int k = 0; k < 4; ++k) {
                MD[(7 + k)  * T + t1] = -2.0 * v[7 + k];
                MD[(11 + k) * T + t1] = -2.0 * v[11 + k];
            }
            MD[15 * T + t1] = v[15];
            EF[0 * T + t1] = ly;
            EF[1 * T + t1] = uy;
            EF[2 * T + t1] = lx;
            EF[3 * T + t1] = ux;
            EF[4 * T + t1] = (float)v[16];
            EF[5 * T + t1] = row[0];        // class id
        }
    }

    cg::this_grid().sync();

    // ---------- phase 2: cost matrix (round-0 cost_kernel, 1024 threads) ----
    __shared__ float wavemin[WPB];
    float perv = (tid < T) ? EF[4 * T + tid] : 1e30f;
    float pm = perv;
#pragma unroll
    for (int off = 32; off > 0; off >>= 1) pm = fminf(pm, __shfl_xor(pm, off));
    if (lane == 0) wavemin[wid] = pm;
    __syncthreads();
    float per_min = wavemin[0];
#pragma unroll
    for (int i = 1; i < WPB; ++i) per_min = fminf(per_min, wavemin[i]);

    const int g = tid >> 9;          // bn half-group: 0 or 1
    const int t = tid & 511;
    if (t >= T) return;

    double m[16];
#pragma unroll
    for (int r = 0; r < 16; ++r) m[r] = MD[r * T + t];   // coalesced 8B

    const float ly = EF[0 * T + t], uy = EF[1 * T + t];
    const float lx = EF[2 * T + t], ux = EF[3 * T + t];
    const float per = EF[4 * T + t];
    const int   id  = (int)EF[5 * T + t];
    const float w = sqrtf(per_min / per);

    const int bnbase = blockIdx.x * KBN + g * (KBN / 2);
#pragma unroll
    for (int j = 0; j < KBN / 2; ++j) {
        const int bn = bnbase + j;
        const float* ob = curves + (size_t)bn * 8;        // wave-uniform
        float o0 = ob[0], o1 = ob[1], o2 = ob[2], o3 = ob[3];
        float o4 = ob[4], o5 = ob[5], o6 = ob[6], o7 = ob[7];
        float a0 = o2, a1 = o3 - o4 - o5 - o2, a2 = o5, a3 = o4;
        float b0 = o0, b1 = o1 - o6 - o7 - o0, b2 = o7, b3 = o6;

        double A0 = a0, A1 = a1, A2 = a2, A3 = a3;
        double B0 = b0, B1 = b1, B2 = b2, B3 = b3;
        double acc = m[15]
            + (A0 * A0 + B0 * B0) * m[0]
            + 2.0 * (A0 * A1 + B0 * B1) * m[1]
            + (2.0 * (A0 * A2 + B0 * B2) + A1 * A1 + B1 * B1) * m[2]
            + 2.0 * (A0 * A3 + A1 * A2 + B0 * B3 + B1 * B2) * m[3]
            + (2.0 * (A1 * A3 + B1 * B3) + A2 * A2 + B2 * B2) * m[4]
            + 2.0 * (A2 * A3 + B2 * B3) * m[5]
            + (A3 * A3 + B3 * B3) * m[6]
            + A0 * m[7]  + A1 * m[8]  + A2 * m[9]  + A3 * m[10]
            + B0 * m[11] + B1 * m[12] + B2 * m[13] + B3 * m[14];

        const float* lg = logits + (size_t)bn * NCLS;     // wave-uniform
        float l0 = lg[0], l1 = lg[1], l2 = lg[2];
        float mx = fmaxf(l0, fmaxf(l1, l2));
        float e0 = __expf(l0 - mx), e1 = __expf(l1 - mx), e2 = __expf(l2 - mx);
        float inv = 1.0f / (e0 + e1 + e2);
        float prob = (id == 0) ? e0 * inv : ((id == 1) ? e1 * inv : e2 * inv);

        float cp = (float)acc * w * 0.1f;
        float cl = 0.5f * (fabsf(b0 - ly) + fabsf(a0 - lx));
        float cu = 0.5f * (fabsf(o1 - uy) + fabsf(o3 - ux));
        out[(size_t)bn * T + t] = -prob + cp + cl + cu;   // coalesced over t
    }
}

extern "C" void kernel_launch(void* const* d_in, const int* in_sizes, int n_in,
                              void* d_out, int out_size, void* d_ws, size_t ws_size,
                              hipStream_t stream) {
    const float* logits  = (const float*)d_in[0];  // (16,128,3)
    const float* curves  = (const float*)d_in[1];  // (16,128,8)
    const float* targets = (const float*)d_in[2];  // (480,149)
    float* out = (float*)d_out;
    char*  ws  = (char*)d_ws;

    double* MD = (double*)(ws + MD_OFF_B);
    float*  EF = (float*) (ws + EF_OFF_B);

    void* kargs[] = {
        (void*)&logits, (void*)&curves, (void*)&targets,
        (void*)&MD, (void*)&EF, (void*)&out
    };
    hipLaunchCooperativeKernel((const void*)fused, dim3(NBLK), dim3(NTHR),
                               kargs, 0, stream);
}

// Round 3
// 90.277 us; speedup vs baseline: 1.3851x; 1.1579x over previous
//
#include <hip/hip_runtime.h>
#include <math.h>

#define BS   16
#define NQ   128
#define NCLS 3
#define T    480
#define P    72
#define BN   (BS * NQ)      // 2048
#define TROW (5 + 2 * P)    // 149
#define TT   32             // targets per t-tile
#define NTT  (T / TT)       // 15 t-tiles
#define BNT  128            // bn per bn-tile
#define NBNT (BN / BNT)     // 16 bn-tiles
#define NTHR 1024
#define WPB  (NTHR / 64)    // 16 waves

// Single STANDARD kernel (no cooperative launch — round-2 showed grid.sync
// costs ~40 us here; round-1 showed the 256 MiB ws poison is unconditional).
// 2D tiling removes the grid-wide dependency:
//   - per[t] (valid count) is cheap -> every block computes ALL 480 via
//     ballot/popcount on coalesced row reads -> per_min is block-local.
//   - fp64 moments are expensive -> each block computes them only for its
//     own 32-target tile (16x redundancy across bn-tiles, ~0.3 us/block),
//     using the round-0 proven coalesced wave-per-target body.
//   - phase C: 128 bn x 32 t costs from LDS moments.
__global__ __launch_bounds__(NTHR) void fused(
    const float* __restrict__ logits,
    const float* __restrict__ curves,
    const float* __restrict__ targets,
    float* __restrict__ out)
{
    __shared__ float  sPER[T];        // 1920 B : valid counts, all targets
    __shared__ double sMD[16 * TT];   // 4096 B : moments, this tile only
    __shared__ float  sEF[5 * TT];    // 640 B  : ly,uy,lx,ux,id, this tile
    __shared__ float  swm[WPB];

    const int tid  = threadIdx.x;
    const int lane = tid & 63;
    const int wid  = tid >> 6;
    const int t0   = blockIdx.y * TT;
    const int bn0  = blockIdx.x * BNT;

    // ---- phase A: per[t] for ALL targets (ballot/popcount, coalesced) ----
    for (int t = wid; t < T; t += WPB) {
        const float* xs = targets + (size_t)t * TROW + 5;
        bool v0 = (xs[lane] >= 0.0f);                       // p = lane < 64
        bool v1 = (lane < 8) ? (xs[64 + lane] >= 0.0f) : false; // p = 64..71
        int cnt = __popcll(__ballot(v0)) + __popcll(__ballot(v1));
        if (lane == 0) sPER[t] = (float)cnt;
    }

    // ---- phase B: fp64 moments for this block's TT targets --------------
    // wave wid handles tl = wid and wid+16 (round-0 body, coalesced loads)
#pragma unroll
    for (int rep = 0; rep < TT / WPB; ++rep) {
        const int tl = wid + rep * WPB;
        const int t  = t0 + tl;
        const float* row = targets + (size_t)t * TROW;
        const float ly = row[1], uy = row[2], lx = row[3], ux = row[4];
        const float dx = ux - lx, dy = uy - ly;
        const float nrm = sqrtf(dx * dx + dy * dy);

        double v[16];
#pragma unroll
        for (int i = 0; i < 16; ++i) v[i] = 0.0;

        for (int p = lane; p < P; p += 64) {
            float tx = row[5 + p];          // coalesced across lanes
            float ty = row[5 + P + p];
            if (tx >= 0.0f) {
                float lamf = dx * (tx - lx) + dy * (ty - ly);
                lamf = lamf / nrm / nrm;    // match reference: dot/nrm/nrm
                double L   = (double)lamf;
                double txd = (double)tx, tyd = (double)ty;
                double lp  = 1.0;
#pragma unroll
                for (int j = 0; j < 7; ++j) {
                    v[j] += lp;
                    if (j < 4) { v[7 + j] += txd * lp; v[11 + j] += tyd * lp; }
                    lp *= L;
                }
                v[15] += txd * txd + tyd * tyd;
            }
        }
#pragma unroll
        for (int off = 32; off > 0; off >>= 1) {
#pragma unroll
            for (int i = 0; i < 16; ++i) v[i] += __shfl_down(v[i], off);
        }
        if (lane == 0) {
#pragma unroll
            for (int j = 0; j < 7; ++j) sMD[j * TT + tl] = v[j];
#pragma unroll
            for (int k = 0; k < 4; ++k) {
                sMD[(7 + k)  * TT + tl] = -2.0 * v[7 + k];
                sMD[(11 + k) * TT + tl] = -2.0 * v[11 + k];
            }
            sMD[15 * TT + tl] = v[15];
            sEF[0 * TT + tl] = ly;
            sEF[1 * TT + tl] = uy;
            sEF[2 * TT + tl] = lx;
            sEF[3 * TT + tl] = ux;
            sEF[4 * TT + tl] = row[0];      // class id
        }
    }
    __syncthreads();

    // ---- per_min over all 480 (block-local, no grid sync needed) ---------
    float pm = (tid < T) ? sPER[tid] : 1e30f;
#pragma unroll
    for (int off = 32; off > 0; off >>= 1) pm = fminf(pm, __shfl_xor(pm, off));
    if (lane == 0) swm[wid] = pm;
    __syncthreads();
    float per_min = swm[0];
#pragma unroll
    for (int i = 1; i < WPB; ++i) per_min = fminf(per_min, swm[i]);

    // ---- phase C: cost for BNT bn x TT t ---------------------------------
    const int tl  = tid & (TT - 1);
    const int bnl = tid >> 5;               // 0..31
    const int t   = t0 + tl;

    double m[16];
#pragma unroll
    for (int r = 0; r < 16; ++r) m[r] = sMD[r * TT + tl];  // 2-way max, free

    const float ly = sEF[0 * TT + tl], uy = sEF[1 * TT + tl];
    const float lx = sEF[2 * TT + tl], ux = sEF[3 * TT + tl];
    const int   id = (int)sEF[4 * TT + tl];
    const float w  = sqrtf(per_min / sPER[t]);

#pragma unroll
    for (int j = 0; j < BNT / 32; ++j) {
        const int bn = bn0 + j * 32 + bnl;
        const float* ob = curves + (size_t)bn * 8;         // 2 bn/wave -> broadcast
        float o0 = ob[0], o1 = ob[1], o2 = ob[2], o3 = ob[3];
        float o4 = ob[4], o5 = ob[5], o6 = ob[6], o7 = ob[7];
        float a0 = o2, a1 = o3 - o4 - o5 - o2, a2 = o5, a3 = o4;
        float b0 = o0, b1 = o1 - o6 - o7 - o0, b2 = o7, b3 = o6;

        double A0 = a0, A1 = a1, A2 = a2, A3 = a3;
        double B0 = b0, B1 = b1, B2 = b2, B3 = b3;
        double acc = m[15]
            + (A0 * A0 + B0 * B0) * m[0]
            + 2.0 * (A0 * A1 + B0 * B1) * m[1]
            + (2.0 * (A0 * A2 + B0 * B2) + A1 * A1 + B1 * B1) * m[2]
            + 2.0 * (A0 * A3 + A1 * A2 + B0 * B3 + B1 * B2) * m[3]
            + (2.0 * (A1 * A3 + B1 * B3) + A2 * A2 + B2 * B2) * m[4]
            + 2.0 * (A2 * A3 + B2 * B3) * m[5]
            + (A3 * A3 + B3 * B3) * m[6]
            + A0 * m[7]  + A1 * m[8]  + A2 * m[9]  + A3 * m[10]
            + B0 * m[11] + B1 * m[12] + B2 * m[13] + B3 * m[14];

        const float* lg = logits + (size_t)bn * NCLS;      // 2 bn/wave -> broadcast
        float l0 = lg[0], l1 = lg[1], l2 = lg[2];
        float mx = fmaxf(l0, fmaxf(l1, l2));
        float e0 = __expf(l0 - mx), e1 = __expf(l1 - mx), e2 = __expf(l2 - mx);
        float inv = 1.0f / (e0 + e1 + e2);
        float prob = (id == 0) ? e0 * inv : ((id == 1) ? e1 * inv : e2 * inv);

        float cp = (float)acc * w * 0.1f;
        float cl = 0.5f * (fabsf(b0 - ly) + fabsf(a0 - lx));
        float cu = 0.5f * (fabsf(o1 - uy) + fabsf(o3 - ux));
        out[(size_t)bn * T + t] = -prob + cp + cl + cu;    // 32-wide segments
    }
}

extern "C" void kernel_launch(void* const* d_in, const int* in_sizes, int n_in,
                              void* d_out, int out_size, void* d_ws, size_t ws_size,
                              hipStream_t stream) {
    const float* logits  = (const float*)d_in[0];  // (16,128,3)
    const float* curves  = (const float*)d_in[1];  // (16,128,8)
    const float* targets = (const float*)d_in[2];  // (480,149)
    (void)d_ws; (void)ws_size;

    fused<<<dim3(NBNT, NTT), NTHR, 0, stream>>>(logits, curves, targets,
                                                (float*)d_out);
}

// Round 4
// 67.198 us; speedup vs baseline: 1.8608x; 1.3434x over previous
//
#include <hip/hip_runtime.h>
#include <math.h>

#define BS   16
#define NQ   128
#define NCLS 3
#define T    480
#define P    72
#define BN   (BS * NQ)      // 2048
#define TROW (5 + 2 * P)    // 149
#define BNB  4              // bn per block in cost kernel

// ws layout (bytes):
//   MD  double[16][T] @ 0      (61440)
//     rows 0..6  : m_j  = sum_valid lam^j            (j=0..6)
//     rows 7..10 : sx_k = -2 * sum_valid tx*lam^k    (k=0..3)
//     rows 11..14: sy_k = -2 * sum_valid ty*lam^k    (k=0..3)
//     row  15    : Q    = sum_valid (tx^2 + ty^2)
//   EF  float[6][T]   @ 61440  (11520): ly, uy, lx, ux, per, id
// (round-1 proved the 256 MiB ws poison fill runs unconditionally -> ws free)
#define MD_OFF_B 0
#define EF_OFF_B 61440

// One wave per target. Lane-parallel moment groups: lane = (psub, mg),
// mg = lane&3 selects the moment stream, psub = lane>>2 the point subset.
// Each lane keeps only FIVE fp64 accumulators (streams of base*L^{0..3} with
// base in {1, L^3, tx, ty} + one extra {cnt, Q}) instead of the old 17-double
// array -> ~35 VGPRs, no scratch spill (rounds 1/3 showed the 16/17-double
// per-lane array spills: VGPR_Count 36/44 << 75 needed, time tracked spill
// executions). Butterfly shrinks 102 -> 20 fp64 shfls.
__global__ __launch_bounds__(64) void moments_kernel(const float* __restrict__ targets,
                                                     double* __restrict__ MD,
                                                     float* __restrict__ EF) {
    const int t    = blockIdx.x;
    const int lane = threadIdx.x;
    const int mg   = lane & 3;        // moment group 0..3
    const int psub = lane >> 2;       // point slot 0..15

    const float* row = targets + (size_t)t * TROW;
    const float ly = row[1], uy = row[2], lx = row[3], ux = row[4];
    const float dx = ux - lx, dy = uy - ly;
    const float nrm = sqrtf(dx * dx + dy * dy);

    double a0 = 0.0, a1 = 0.0, a2 = 0.0, a3 = 0.0, e = 0.0;

#pragma unroll
    for (int k = 0; k < 5; ++k) {
        const int p = psub + 16 * k;           // 16 points/iter, 4-lane broadcast
        if (p < P) {
            float tx = row[5 + p];
            float ty = row[5 + P + p];
            if (tx >= 0.0f) {
                float lamf = dx * (tx - lx) + dy * (ty - ly);
                lamf = lamf / nrm / nrm;       // match reference: dot/nrm/nrm
                double L  = (double)lamf;
                double L2 = L * L;             // same association as old lp chain
                double L3 = L2 * L;
                double txd = (double)tx, tyd = (double)ty;
                double base = (mg == 0) ? 1.0 : (mg == 1) ? L3
                            : (mg == 2) ? txd : tyd;
                double esel = (mg == 0) ? 1.0
                            : (mg == 1) ? (txd * txd + tyd * tyd) : 0.0;
                a0 += base;
                a1 += base * L;
                a2 += base * L2;
                a3 += base * L3;
                e  += esel;
            }
        }
    }

    // reduce across the 16 psub slots (xor butterfly over strides 4..32)
#pragma unroll
    for (int off = 4; off <= 32; off <<= 1) {
        a0 += __shfl_xor(a0, off);
        a1 += __shfl_xor(a1, off);
        a2 += __shfl_xor(a2, off);
        a3 += __shfl_xor(a3, off);
        e  += __shfl_xor(e,  off);
    }

    if (psub == 0) {                  // lanes 0..3, one per moment group
        if (mg == 0) {                // m0..m3, per-count
            MD[0 * T + t] = a0;  MD[1 * T + t] = a1;
            MD[2 * T + t] = a2;  MD[3 * T + t] = a3;
            EF[4 * T + t] = (float)e;
        } else if (mg == 1) {         // m4..m6 = L^3 * L^{1,2,3}, Q
            MD[4 * T + t] = a1;  MD[5 * T + t] = a2;  MD[6 * T + t] = a3;
            MD[15 * T + t] = e;
        } else if (mg == 2) {         // sx_k
            MD[7 * T + t]  = -2.0 * a0;  MD[8 * T + t]  = -2.0 * a1;
            MD[9 * T + t]  = -2.0 * a2;  MD[10 * T + t] = -2.0 * a3;
        } else {                      // sy_k + header
            MD[11 * T + t] = -2.0 * a0;  MD[12 * T + t] = -2.0 * a1;
            MD[13 * T + t] = -2.0 * a2;  MD[14 * T + t] = -2.0 * a3;
            EF[0 * T + t] = ly;
            EF[1 * T + t] = uy;
            EF[2 * T + t] = lx;
            EF[3 * T + t] = ux;
            EF[5 * T + t] = row[0];   // class id
        }
    }
}

// UNCHANGED from the round-0 proven-fast kernel.
// thread = t, block = BNB bn's. Per-bn prep (coeffs + softmax) inlined;
// quadratic-form terms folded directly into the 16-term fp64 dot.
__global__ __launch_bounds__(512) void cost_kernel(const float* __restrict__ logits,
                                                   const float* __restrict__ curves,
                                                   const double* __restrict__ MD,
                                                   const float* __restrict__ EF,
                                                   float* __restrict__ out) {
    __shared__ float wavemin[8];
    int t    = threadIdx.x;
    int bn0  = blockIdx.x * BNB;
    int lane = t & 63;
    int wid  = t >> 6;

    // per_min across all 480 t (block covers all t, so this is global).
    // w[t] = sqrt(total/per)/max(sqrt(total/per)) = sqrt(per_min/per)
    float per = (t < T) ? EF[4 * T + t] : 1e30f;
    float pm = per;
#pragma unroll
    for (int off = 32; off > 0; off >>= 1) pm = fminf(pm, __shfl_xor(pm, off));
    if (lane == 0) wavemin[wid] = pm;
    __syncthreads();
    float per_min = wavemin[0];
#pragma unroll
    for (int i = 1; i < 8; ++i) per_min = fminf(per_min, wavemin[i]);

    if (t >= T) return;
    float w = sqrtf(per_min / per);

    double m[16];
#pragma unroll
    for (int r = 0; r < 16; ++r) m[r] = MD[r * T + t];   // coalesced
    float ly = EF[0 * T + t], uy = EF[1 * T + t];
    float lx = EF[2 * T + t], ux = EF[3 * T + t];
    int   id = (int)EF[5 * T + t];

#pragma unroll
    for (int j = 0; j < BNB; ++j) {
        int bn = bn0 + j;
        const float* ob = curves + (size_t)bn * 8;       // uniform -> s_load
        float o0 = ob[0], o1 = ob[1], o2 = ob[2], o3 = ob[3];
        float o4 = ob[4], o5 = ob[5], o6 = ob[6], o7 = ob[7];
        float a0 = o2, a1 = o3 - o4 - o5 - o2, a2 = o5, a3 = o4;
        float b0 = o0, b1 = o1 - o6 - o7 - o0, b2 = o7, b3 = o6;

        double A0 = a0, A1 = a1, A2 = a2, A3 = a3;
        double B0 = b0, B1 = b1, B2 = b2, B3 = b3;
        double acc = m[15]
            + (A0 * A0 + B0 * B0) * m[0]
            + 2.0 * (A0 * A1 + B0 * B1) * m[1]
            + (2.0 * (A0 * A2 + B0 * B2) + A1 * A1 + B1 * B1) * m[2]
            + 2.0 * (A0 * A3 + A1 * A2 + B0 * B3 + B1 * B2) * m[3]
            + (2.0 * (A1 * A3 + B1 * B3) + A2 * A2 + B2 * B2) * m[4]
            + 2.0 * (A2 * A3 + B2 * B3) * m[5]
            + (A3 * A3 + B3 * B3) * m[6]
            + A0 * m[7]  + A1 * m[8]  + A2 * m[9]  + A3 * m[10]
            + B0 * m[11] + B1 * m[12] + B2 * m[13] + B3 * m[14];

        const float* lg = logits + (size_t)bn * NCLS;    // uniform -> s_load
        float l0 = lg[0], l1 = lg[1], l2 = lg[2];
        float mx = fmaxf(l0, fmaxf(l1, l2));
        float e0 = __expf(l0 - mx), e1 = __expf(l1 - mx), e2 = __expf(l2 - mx);
        float inv = 1.0f / (e0 + e1 + e2);
        float prob = (id == 0) ? e0 * inv : ((id == 1) ? e1 * inv : e2 * inv);

        float cp = (float)acc * w * 0.1f;
        float cl = 0.5f * (fabsf(b0 - ly) + fabsf(a0 - lx));   // |ob0-ly|+|ob2-lx|
        float cu = 0.5f * (fabsf(o1 - uy) + fabsf(o3 - ux));   // |ob1-uy|+|ob3-ux|
        out[(size_t)bn * T + t] = -prob + cp + cl + cu;        // coalesced
    }
}

extern "C" void kernel_launch(void* const* d_in, const int* in_sizes, int n_in,
                              void* d_out, int out_size, void* d_ws, size_t ws_size,
                              hipStream_t stream) {
    const float* logits  = (const float*)d_in[0];  // (16,128,3)
    const float* curves  = (const float*)d_in[1];  // (16,128,8)
    const float* targets = (const float*)d_in[2];  // (480,149)
    float* out = (float*)d_out;
    char*  ws  = (char*)d_ws;

    double* MD = (double*)(ws + MD_OFF_B);
    float*  EF = (float*) (ws + EF_OFF_B);

    moments_kernel<<<T, 64, 0, stream>>>(targets, MD, EF);
    cost_kernel<<<BN / BNB, 512, 0, stream>>>(logits, curves, MD, EF, out);
}